// Round 1
// baseline (10791.274 us; speedup 1.0000x reference)
//
#include <hip/hip_runtime.h>
#include <hip/hip_bf16.h>

// Problem constants
#define BB   8
#define TT   16
#define CIN  32
#define HID  64
#define HH   64
#define WW   64
#define CC   96          // CIN + HID combined channels
#define OC   256         // 4 * HID
#define ICCH 16          // input-channel chunk staged in LDS
#define EPS  1e-3f
#define NEG_SLOPE 0.01f

__device__ __forceinline__ float sigmoidf_(float x) {
    return 1.0f / (1.0f + __expf(-x));
}

// One timestep: conv(concat(x_t, h)) + bias -> gates -> c/h update -> leaky out
// grid: (16 spatial tiles, B, 8 hid-groups); block: 256 (16x16 pixels)
// Each block computes 32 output channels: hid in [grp*8, grp*8+8) x 4 gates.
__global__ __launch_bounds__(256, 4) void conv_step(
    const float* __restrict__ x, const float* __restrict__ w,
    const float* __restrict__ bias,
    const float* __restrict__ h_in, float* __restrict__ h_out,
    float* __restrict__ c, float* __restrict__ out,
    float* __restrict__ sums, int t)
{
    const int tile = blockIdx.x;            // 0..15
    const int b    = blockIdx.y;            // 0..7
    const int grp  = blockIdx.z;            // 0..7
    const int ty0 = (tile >> 2) << 4;
    const int tx0 = (tile & 3) << 4;
    const int tid = threadIdx.x;
    const int px = tid & 15, py = tid >> 4;
    const int gy = ty0 + py, gx = tx0 + px;

    __shared__ float s_in[ICCH][18 * 18];      // 20736 B
    __shared__ float s_w[32][ICCH * 9];        // 18432 B

    float acc[32];
#pragma unroll
    for (int i = 0; i < 32; ++i) acc[i] = 0.0f;

    for (int icc = 0; icc < CC; icc += ICCH) {
        // stage input chunk (16 ch x 18x18 halo tile), zero-padded at borders
        for (int idx = tid; idx < ICCH * 324; idx += 256) {
            int ic  = idx / 324;
            int r   = idx - ic * 324;
            int row = r / 18, col = r - row * 18;
            int iy = ty0 + row - 1, ix = tx0 + col - 1;
            float v = 0.0f;
            if (iy >= 0 && iy < HH && ix >= 0 && ix < WW) {
                int cch = icc + ic;
                if (cch < CIN)
                    v = x[(((size_t)(b * TT + t) * CIN + cch) * HH + iy) * WW + ix];
                else
                    v = h_in[(((size_t)b * HID + (cch - CIN)) * HH + iy) * WW + ix];
            }
            s_in[ic][r] = v;
        }
        // stage weights for this group's 32 ocs over this ic chunk
        for (int idx = tid; idx < 32 * ICCH * 9; idx += 256) {
            int oc_l = idx / (ICCH * 9);
            int r    = idx - oc_l * (ICCH * 9);   // r = ic*9 + k
            int gate = oc_l >> 3, j = oc_l & 7;
            int oc   = gate * HID + grp * 8 + j;
            int ic   = r / 9, k = r - ic * 9;
            s_w[oc_l][r] = w[((size_t)oc * CC + (icc + ic)) * 9 + k];
        }
        __syncthreads();

#pragma unroll 2
        for (int ic = 0; ic < ICCH; ++ic) {
            float in9[9];
#pragma unroll
            for (int ky = 0; ky < 3; ++ky)
#pragma unroll
                for (int kx = 0; kx < 3; ++kx)
                    in9[ky * 3 + kx] = s_in[ic][(py + ky) * 18 + (px + kx)];
#pragma unroll
            for (int oc_l = 0; oc_l < 32; ++oc_l) {
                float a = acc[oc_l];
                const float* wr = &s_w[oc_l][ic * 9];
#pragma unroll
                for (int k = 0; k < 9; ++k) a = fmaf(wr[k], in9[k], a);
                acc[oc_l] = a;
            }
        }
        __syncthreads();
    }

    // epilogue: gate math for 8 hid channels; acc[gate*8 + j]
    float out_local[8];
#pragma unroll
    for (int j = 0; j < 8; ++j) {
        int hid = grp * 8 + j;
        float ci = acc[0 * 8 + j] + bias[0 * HID + hid];
        float cf = acc[1 * 8 + j] + bias[1 * HID + hid];
        float co = acc[2 * 8 + j] + bias[2 * HID + hid];
        float cg = acc[3 * 8 + j] + bias[3 * HID + hid];
        size_t cidx = (((size_t)b * HID + hid) * HH + gy) * WW + gx;
        float c_old = c[cidx];
        float c_new = sigmoidf_(cf) * c_old + sigmoidf_(ci) * tanhf(cg);
        float h_new = sigmoidf_(co) * tanhf(c_new);
        c[cidx] = c_new;
        h_out[cidx] = h_new;
        float ov = (h_new >= 0.0f) ? h_new : NEG_SLOPE * h_new;
        out[((((size_t)b * TT + t) * HID + hid) * HH + gy) * WW + gx] = ov;
        out_local[j] = ov;
    }

    // per-channel sum / sumsq: wave-reduce then one atomic per wave
#pragma unroll
    for (int j = 0; j < 8; ++j) {
        float s  = out_local[j];
        float s2 = s * s;
#pragma unroll
        for (int m = 32; m > 0; m >>= 1) {
            s  += __shfl_xor(s, m);
            s2 += __shfl_xor(s2, m);
        }
        if ((tid & 63) == 0) {
            atomicAdd(&sums[grp * 8 + j], s);
            atomicAdd(&sums[HID + grp * 8 + j], s2);
        }
    }
}

__global__ void finalize_stats(const float* __restrict__ sums,
                               float* __restrict__ stats,
                               const float* __restrict__ gamma,
                               const float* __restrict__ beta)
{
    int hid = threadIdx.x;   // 64 threads
    const float n = (float)((size_t)BB * TT * HH * WW);   // 524288
    float mean = sums[hid] / n;
    float var  = sums[HID + hid] / n - mean * mean;
    float inv  = rsqrtf(var + EPS);
    float sc   = gamma[hid] * inv;
    stats[hid]       = sc;                       // scale
    stats[HID + hid] = beta[hid] - mean * sc;    // shift
}

__global__ __launch_bounds__(256) void normalize_k(
    float* __restrict__ out, const float* __restrict__ stats)
{
    const size_t N = (size_t)BB * TT * HID * HH * WW;   // 33,554,432
    size_t i = ((size_t)blockIdx.x * blockDim.x + threadIdx.x) * 4;
    size_t stride = (size_t)gridDim.x * blockDim.x * 4;
    for (; i < N; i += stride) {
        int ch = (int)((i >> 12) & (HID - 1));   // H*W = 4096 per channel plane
        float sc = stats[ch], sh = stats[HID + ch];
        float4 v = *(float4*)(out + i);
        v.x = fmaf(v.x, sc, sh);
        v.y = fmaf(v.y, sc, sh);
        v.z = fmaf(v.z, sc, sh);
        v.w = fmaf(v.w, sc, sh);
        *(float4*)(out + i) = v;
    }
}

extern "C" void kernel_launch(void* const* d_in, const int* in_sizes, int n_in,
                              void* d_out, int out_size, void* d_ws, size_t ws_size,
                              hipStream_t stream) {
    const float* x     = (const float*)d_in[0];
    const float* w     = (const float*)d_in[1];
    const float* bias  = (const float*)d_in[2];
    const float* gamma = (const float*)d_in[3];
    const float* beta  = (const float*)d_in[4];
    float* out = (float*)d_out;
    float* ws  = (float*)d_ws;

    const size_t BHW = (size_t)BB * HID * HH * WW;   // 2,097,152 floats
    float* hA    = ws;
    float* hB    = ws + BHW;
    float* c     = ws + 2 * BHW;
    float* sums  = ws + 3 * BHW;       // 128 floats
    float* stats = sums + 128;         // 128 floats

    hipMemsetAsync(hA, 0, BHW * sizeof(float), stream);
    hipMemsetAsync(c, 0, (BHW + 256) * sizeof(float), stream);  // c + sums + stats

    float* hin = hA;
    float* hout = hB;
    for (int t = 0; t < TT; ++t) {
        conv_step<<<dim3(16, BB, 8), 256, 0, stream>>>(
            x, w, bias, hin, hout, c, out, sums, t);
        float* tmp = hin; hin = hout; hout = tmp;
    }
    finalize_stats<<<1, 64, 0, stream>>>(sums, stats, gamma, beta);
    normalize_k<<<8192, 256, 0, stream>>>(out, stats);
}

// Round 2
// 9041.931 us; speedup vs baseline: 1.1935x; 1.1935x over previous
//
#include <hip/hip_runtime.h>
#include <hip/hip_bf16.h>

// Problem constants
#define BB   8
#define TT   16
#define CIN  32
#define HID  64
#define HH   64
#define WW   64
#define CC   96          // CIN + HID combined channels
#define OC   256         // 4 * HID
#define ICCH 16          // input-channel chunk staged in LDS
#define NCHK 6           // CC / ICCH
#define EPS  1e-3f
#define NEG_SLOPE 0.01f

// packed weight layout: [grp(8)][chunk(6)][ic(16)][oc_l(32)][k(9)]
#define WPK_PER_CHUNK (ICCH * 32 * 9)          // 4608 floats
#define WPK_TOTAL     (8 * NCHK * WPK_PER_CHUNK) // 221184 floats

__device__ __forceinline__ float sigmoidf_(float x) {
    return 1.0f / (1.0f + __expf(-x));
}

// one-shot: repack conv weights into wave-uniform streaming order so the
// conv inner loop consumes them via wide s_load (scalar pipe, not LDS/VALU)
__global__ __launch_bounds__(256) void pack_w(const float* __restrict__ w,
                                              float* __restrict__ wpk) {
    int idx = blockIdx.x * 256 + threadIdx.x;
    if (idx >= WPK_TOTAL) return;
    int k    = idx % 9;
    int t    = idx / 9;
    int oc_l = t % 32; t /= 32;
    int ic   = t % ICCH; t /= ICCH;
    int chunk = t % NCHK;
    int grp   = t / NCHK;
    int oc  = (oc_l >> 3) * HID + grp * 8 + (oc_l & 7);  // gate*HID + hid
    int icg = chunk * ICCH + ic;
    wpk[idx] = w[((size_t)oc * CC + icg) * 9 + k];
}

// One timestep: conv(concat(x_t, h)) + bias -> gates -> c/h update -> leaky out
// grid: (16 spatial tiles, B, 8 hid-groups); block: 256 (16x16 pixels)
// Each block computes 32 output channels: hid in [grp*8, grp*8+8) x 4 gates.
// Weights come from wpk via uniform (scalar) loads -> SGPR operand of v_fmac.
__global__ __launch_bounds__(256, 4) void conv_step(
    const float* __restrict__ x, const float* __restrict__ wpk,
    const float* __restrict__ bias,
    const float* __restrict__ h_in, float* __restrict__ h_out,
    float* __restrict__ c, float* __restrict__ out,
    float* __restrict__ sums, int t)
{
    const int tile = blockIdx.x;            // 0..15
    const int b    = blockIdx.y;            // 0..7
    const int grp  = blockIdx.z;            // 0..7
    const int ty0 = (tile >> 2) << 4;
    const int tx0 = (tile & 3) << 4;
    const int tid = threadIdx.x;
    const int px = tid & 15, py = tid >> 4;
    const int gy = ty0 + py, gx = tx0 + px;

    __shared__ float s_in[ICCH][18 * 18];      // 20736 B

    float acc[32];
#pragma unroll
    for (int g = 0; g < 4; ++g)
#pragma unroll
        for (int j = 0; j < 8; ++j)
            acc[g * 8 + j] = bias[g * HID + grp * 8 + j];

    for (int icc6 = 0; icc6 < NCHK; ++icc6) {
        const int icc = icc6 * ICCH;
        // stage input chunk (16 ch x 18x18 halo tile), zero-padded at borders
        for (int idx = tid; idx < ICCH * 324; idx += 256) {
            int ic  = idx / 324;
            int r   = idx - ic * 324;
            int row = r / 18, col = r - row * 18;
            int iy = ty0 + row - 1, ix = tx0 + col - 1;
            float v = 0.0f;
            if (iy >= 0 && iy < HH && ix >= 0 && ix < WW) {
                int cch = icc + ic;
                if (cch < CIN)
                    v = x[(((size_t)(b * TT + t) * CIN + cch) * HH + iy) * WW + ix];
                else
                    v = h_in[(((size_t)b * HID + (cch - CIN)) * HH + iy) * WW + ix];
            }
            s_in[ic][r] = v;
        }
        __syncthreads();

        const float* __restrict__ wp = wpk + (size_t)(grp * NCHK + icc6) * WPK_PER_CHUNK;
#pragma unroll 1
        for (int ic = 0; ic < ICCH; ++ic) {
            float in9[9];
#pragma unroll
            for (int ky = 0; ky < 3; ++ky)
#pragma unroll
                for (int kx = 0; kx < 3; ++kx)
                    in9[ky * 3 + kx] = s_in[ic][(py + ky) * 18 + (px + kx)];
            const float* __restrict__ wr = wp + ic * (32 * 9);
#pragma unroll
            for (int oc_l = 0; oc_l < 32; ++oc_l) {
                float a = acc[oc_l];
#pragma unroll
                for (int k = 0; k < 9; ++k)
                    a = fmaf(wr[oc_l * 9 + k], in9[k], a);
                acc[oc_l] = a;
            }
        }
        __syncthreads();
    }

    // epilogue: gate math for 8 hid channels; acc[gate*8 + j]
    float out_local[8];
#pragma unroll
    for (int j = 0; j < 8; ++j) {
        int hid = grp * 8 + j;
        float ci = acc[0 * 8 + j];
        float cf = acc[1 * 8 + j];
        float co = acc[2 * 8 + j];
        float cg = acc[3 * 8 + j];
        size_t cidx = (((size_t)b * HID + hid) * HH + gy) * WW + gx;
        float c_old = c[cidx];
        float c_new = sigmoidf_(cf) * c_old + sigmoidf_(ci) * tanhf(cg);
        float h_new = sigmoidf_(co) * tanhf(c_new);
        c[cidx] = c_new;
        h_out[cidx] = h_new;
        float ov = (h_new >= 0.0f) ? h_new : NEG_SLOPE * h_new;
        out[((((size_t)b * TT + t) * HID + hid) * HH + gy) * WW + gx] = ov;
        out_local[j] = ov;
    }

    // per-channel sum / sumsq: wave-reduce then one atomic per wave
#pragma unroll
    for (int j = 0; j < 8; ++j) {
        float s  = out_local[j];
        float s2 = s * s;
#pragma unroll
        for (int m = 32; m > 0; m >>= 1) {
            s  += __shfl_xor(s, m);
            s2 += __shfl_xor(s2, m);
        }
        if ((tid & 63) == 0) {
            atomicAdd(&sums[grp * 8 + j], s);
            atomicAdd(&sums[HID + grp * 8 + j], s2);
        }
    }
}

__global__ void finalize_stats(const float* __restrict__ sums,
                               float* __restrict__ stats,
                               const float* __restrict__ gamma,
                               const float* __restrict__ beta)
{
    int hid = threadIdx.x;   // 64 threads
    const float n = (float)((size_t)BB * TT * HH * WW);   // 524288
    float mean = sums[hid] / n;
    float var  = sums[HID + hid] / n - mean * mean;
    float inv  = rsqrtf(var + EPS);
    float sc   = gamma[hid] * inv;
    stats[hid]       = sc;                       // scale
    stats[HID + hid] = beta[hid] - mean * sc;    // shift
}

__global__ __launch_bounds__(256) void normalize_k(
    float* __restrict__ out, const float* __restrict__ stats)
{
    const size_t N = (size_t)BB * TT * HID * HH * WW;   // 33,554,432
    size_t i = ((size_t)blockIdx.x * blockDim.x + threadIdx.x) * 4;
    size_t stride = (size_t)gridDim.x * blockDim.x * 4;
    for (; i < N; i += stride) {
        int ch = (int)((i >> 12) & (HID - 1));   // H*W = 4096 per channel plane
        float sc = stats[ch], sh = stats[HID + ch];
        float4 v = *(float4*)(out + i);
        v.x = fmaf(v.x, sc, sh);
        v.y = fmaf(v.y, sc, sh);
        v.z = fmaf(v.z, sc, sh);
        v.w = fmaf(v.w, sc, sh);
        *(float4*)(out + i) = v;
    }
}

extern "C" void kernel_launch(void* const* d_in, const int* in_sizes, int n_in,
                              void* d_out, int out_size, void* d_ws, size_t ws_size,
                              hipStream_t stream) {
    const float* x     = (const float*)d_in[0];
    const float* w     = (const float*)d_in[1];
    const float* bias  = (const float*)d_in[2];
    const float* gamma = (const float*)d_in[3];
    const float* beta  = (const float*)d_in[4];
    float* out = (float*)d_out;
    float* ws  = (float*)d_ws;

    const size_t BHW = (size_t)BB * HID * HH * WW;   // 2,097,152 floats
    float* hA    = ws;
    float* hB    = ws + BHW;
    float* c     = ws + 2 * BHW;
    float* sums  = ws + 3 * BHW;       // 128 floats
    float* stats = sums + 128;         // 128 floats
    float* wpk   = stats + 128;        // 221184 floats, 64B-aligned

    hipMemsetAsync(hA, 0, BHW * sizeof(float), stream);
    hipMemsetAsync(c, 0, (BHW + 256) * sizeof(float), stream);  // c + sums + stats

    pack_w<<<(WPK_TOTAL + 255) / 256, 256, 0, stream>>>(w, wpk);

    float* hin = hA;
    float* hout = hB;
    for (int t = 0; t < TT; ++t) {
        conv_step<<<dim3(16, BB, 8), 256, 0, stream>>>(
            x, wpk, bias, hin, hout, c, out, sums, t);
        float* tmp = hin; hin = hout; hout = tmp;
    }
    finalize_stats<<<1, 64, 0, stream>>>(sums, stats, gamma, beta);
    normalize_k<<<8192, 256, 0, stream>>>(out, stats);
}

// Round 3
// 5438.275 us; speedup vs baseline: 1.9843x; 1.6626x over previous
//
#include <hip/hip_runtime.h>
#include <hip/hip_bf16.h>

// Problem constants
#define BB   8
#define TT   16
#define CIN  32
#define HID  64
#define HH   64
#define WW   64
#define CC   96          // CIN + HID combined channels
#define ICCH 4           // input channels staged per LDS chunk
#define NCHK 24          // CC / ICCH
#define NGRP 32          // hid-groups (2 hids each)
#define OCPB 8           // output chans per block = 4 gates x 2 hids
#define SROW 70          // LDS row stride (floats), odd-ish to spread banks
#define EPS  1e-3f
#define NEG_SLOPE 0.01f

// packed weight layout: [grp(32)][chunk(24)][ic(4)][k(9)][oc_l(8)]
#define WPK_PER_CHUNK (ICCH * 9 * OCPB)            // 288 floats
#define WPK_TOTAL     (NGRP * NCHK * WPK_PER_CHUNK) // 221184 floats

__device__ __forceinline__ float sigmoidf_(float x) {
    return 1.0f / (1.0f + __expf(-x));
}

// one-shot repack of conv weights into block-streaming order
__global__ __launch_bounds__(256) void pack_w(const float* __restrict__ w,
                                              float* __restrict__ wpk) {
    int idx = blockIdx.x * 256 + threadIdx.x;
    if (idx >= WPK_TOTAL) return;
    int oc_l = idx % 8;          int u = idx / 8;
    int k    = u % 9;            u /= 9;
    int ic   = u % ICCH;         u /= ICCH;
    int chunk = u % NCHK;
    int grp   = u / NCHK;
    int gate = oc_l >> 1, j = oc_l & 1;
    int hid  = grp * 2 + j;
    int oc   = gate * HID + hid;
    int icg  = chunk * ICCH + ic;
    wpk[idx] = w[((size_t)oc * CC + icg) * 9 + k];
}

// One timestep. grid: (4 ybands, B, 32 grp); block 256.
// Thread: 4 horizontal pixels (x = 4*(tid&15)+p), row y = band*16 + (tid>>4).
// Block computes 8 ocs = 4 gates x 2 hids; epilogue fuses LSTM gate math.
__global__ __launch_bounds__(256, 4) void conv_step(
    const float* __restrict__ x, const float* __restrict__ wpk,
    const float* __restrict__ bias,
    const float* __restrict__ h_in, float* __restrict__ h_out,
    float* __restrict__ c, float* __restrict__ out,
    float* __restrict__ sums, int tstep)
{
    const int band = blockIdx.x;            // 0..3
    const int b    = blockIdx.y;            // 0..7
    const int grp  = blockIdx.z;            // 0..31
    const int y0   = band * 16;
    const int tid  = threadIdx.x;
    const int ty   = tid >> 4;              // 0..15
    const int x0   = (tid & 15) * 4;        // 0,4,...,60
    const int y    = y0 + ty;

    __shared__ float s_in[ICCH * 18 * SROW];   // 4*18*70*4 = 20160 B
    __shared__ float s_w[WPK_PER_CHUNK];       // 1152 B

    float acc[OCPB][4];
#pragma unroll
    for (int g = 0; g < 4; ++g)
#pragma unroll
        for (int j = 0; j < 2; ++j) {
            float bv = bias[g * HID + grp * 2 + j];
#pragma unroll
            for (int p = 0; p < 4; ++p) acc[g * 2 + j][p] = bv;
        }

#pragma unroll 1
    for (int chunk = 0; chunk < NCHK; ++chunk) {
        // stage input chunk: 4 ch x 18 halo rows x 66 cols (sidx = imgx+1)
        for (int idx = tid; idx < ICCH * 18 * 66; idx += 256) {
            int ic  = idx / (18 * 66);
            int r   = idx - ic * (18 * 66);
            int row = r / 66, col = r - row * 66;
            int iy = y0 + row - 1, ix = col - 1;
            float v = 0.0f;
            if (iy >= 0 && iy < HH && ix >= 0 && ix < WW) {
                int cch = chunk * ICCH + ic;
                if (cch < CIN)
                    v = x[(((size_t)(b * TT + tstep) * CIN + cch) * HH + iy) * WW + ix];
                else
                    v = h_in[(((size_t)b * HID + (cch - CIN)) * HH + iy) * WW + ix];
            }
            s_in[ic * (18 * SROW) + row * SROW + col] = v;
        }
        // stage weights for this chunk: [ic][k][oc8] = 288 floats
        {
            const float* wp = wpk + ((size_t)grp * NCHK + chunk) * WPK_PER_CHUNK;
            for (int idx = tid; idx < WPK_PER_CHUNK; idx += 256)
                s_w[idx] = wp[idx];
        }
        __syncthreads();

#pragma unroll 1
        for (int ic = 0; ic < ICCH; ++ic) {
            // input window: rows y-1..y+1, img cols x0-1..x0+4 -> sidx x0..x0+5
            float r_in[3][6];
#pragma unroll
            for (int ky = 0; ky < 3; ++ky) {
                const float* rp = &s_in[ic * (18 * SROW) + (ty + ky) * SROW + x0];
                float2 a = *(const float2*)(rp + 0);
                float2 bb = *(const float2*)(rp + 2);
                float2 cc2 = *(const float2*)(rp + 4);
                r_in[ky][0] = a.x;  r_in[ky][1] = a.y;
                r_in[ky][2] = bb.x; r_in[ky][3] = bb.y;
                r_in[ky][4] = cc2.x; r_in[ky][5] = cc2.y;
            }
#pragma unroll
            for (int ky = 0; ky < 3; ++ky) {
#pragma unroll
                for (int kx = 0; kx < 3; ++kx) {
                    const float* wb = &s_w[((ic * 9) + ky * 3 + kx) * 8];
                    float4 wa = *(const float4*)(wb);
                    float4 wc = *(const float4*)(wb + 4);
                    float w8[8] = {wa.x, wa.y, wa.z, wa.w, wc.x, wc.y, wc.z, wc.w};
#pragma unroll
                    for (int o = 0; o < 8; ++o)
#pragma unroll
                        for (int p = 0; p < 4; ++p)
                            acc[o][p] = fmaf(w8[o], r_in[ky][kx + p], acc[o][p]);
                }
            }
        }
        __syncthreads();
    }

    // epilogue: LSTM gate math, 2 hids x 4 px; acc[gate*2+j][p]
    float osum[2] = {0.f, 0.f}, osum2[2] = {0.f, 0.f};
#pragma unroll
    for (int j = 0; j < 2; ++j) {
        int hid = grp * 2 + j;
        size_t base = (((size_t)b * HID + hid) * HH + y) * WW + x0;
        size_t obase = ((((size_t)b * TT + tstep) * HID + hid) * HH + y) * WW + x0;
#pragma unroll
        for (int p = 0; p < 4; ++p) {
            float ci = acc[0 * 2 + j][p];
            float cf = acc[1 * 2 + j][p];
            float co = acc[2 * 2 + j][p];
            float cg = acc[3 * 2 + j][p];
            float c_old = c[base + p];
            float c_new = sigmoidf_(cf) * c_old + sigmoidf_(ci) * tanhf(cg);
            float h_new = sigmoidf_(co) * tanhf(c_new);
            c[base + p] = c_new;
            h_out[base + p] = h_new;
            float ov = (h_new >= 0.0f) ? h_new : NEG_SLOPE * h_new;
            out[obase + p] = ov;
            osum[j] += ov;
            osum2[j] += ov * ov;
        }
    }

    // per-channel sum / sumsq: wave-reduce then one atomic per wave per hid
#pragma unroll
    for (int j = 0; j < 2; ++j) {
        float s = osum[j], s2 = osum2[j];
#pragma unroll
        for (int m = 32; m > 0; m >>= 1) {
            s  += __shfl_xor(s, m);
            s2 += __shfl_xor(s2, m);
        }
        if ((tid & 63) == 0) {
            atomicAdd(&sums[grp * 2 + j], s);
            atomicAdd(&sums[HID + grp * 2 + j], s2);
        }
    }
}

__global__ void finalize_stats(const float* __restrict__ sums,
                               float* __restrict__ stats,
                               const float* __restrict__ gamma,
                               const float* __restrict__ beta)
{
    int hid = threadIdx.x;   // 64 threads
    const float n = (float)((size_t)BB * TT * HH * WW);   // 524288
    float mean = sums[hid] / n;
    float var  = sums[HID + hid] / n - mean * mean;
    float inv  = rsqrtf(var + EPS);
    float sc   = gamma[hid] * inv;
    stats[hid]       = sc;                       // scale
    stats[HID + hid] = beta[hid] - mean * sc;    // shift
}

__global__ __launch_bounds__(256) void normalize_k(
    float* __restrict__ out, const float* __restrict__ stats)
{
    const size_t N = (size_t)BB * TT * HID * HH * WW;   // 33,554,432
    size_t i = ((size_t)blockIdx.x * blockDim.x + threadIdx.x) * 4;
    size_t stride = (size_t)gridDim.x * blockDim.x * 4;
    for (; i < N; i += stride) {
        int ch = (int)((i >> 12) & (HID - 1));   // H*W = 4096 per channel plane
        float sc = stats[ch], sh = stats[HID + ch];
        float4 v = *(float4*)(out + i);
        v.x = fmaf(v.x, sc, sh);
        v.y = fmaf(v.y, sc, sh);
        v.z = fmaf(v.z, sc, sh);
        v.w = fmaf(v.w, sc, sh);
        *(float4*)(out + i) = v;
    }
}

extern "C" void kernel_launch(void* const* d_in, const int* in_sizes, int n_in,
                              void* d_out, int out_size, void* d_ws, size_t ws_size,
                              hipStream_t stream) {
    const float* x     = (const float*)d_in[0];
    const float* w     = (const float*)d_in[1];
    const float* bias  = (const float*)d_in[2];
    const float* gamma = (const float*)d_in[3];
    const float* beta  = (const float*)d_in[4];
    float* out = (float*)d_out;
    float* ws  = (float*)d_ws;

    const size_t BHW = (size_t)BB * HID * HH * WW;   // 2,097,152 floats
    float* hA    = ws;
    float* hB    = ws + BHW;
    float* c     = ws + 2 * BHW;
    float* sums  = ws + 3 * BHW;       // 128 floats
    float* stats = sums + 128;         // 128 floats
    float* wpk   = stats + 128;        // 221184 floats

    hipMemsetAsync(hA, 0, BHW * sizeof(float), stream);
    hipMemsetAsync(c, 0, (BHW + 256) * sizeof(float), stream);  // c + sums + stats

    pack_w<<<(WPK_TOTAL + 255) / 256, 256, 0, stream>>>(w, wpk);

    float* hin = hA;
    float* hout = hB;
    for (int t = 0; t < TT; ++t) {
        conv_step<<<dim3(4, BB, NGRP), 256, 0, stream>>>(
            x, wpk, bias, hin, hout, c, out, sums, t);
        float* tmp = hin; hin = hout; hout = tmp;
    }
    finalize_stats<<<1, 64, 0, stream>>>(sums, stats, gamma, beta);
    normalize_k<<<8192, 256, 0, stream>>>(out, stats);
}

// Round 4
// 818.627 us; speedup vs baseline: 13.1822x; 6.6432x over previous
//
#include <hip/hip_runtime.h>
#include <hip/hip_bf16.h>

#define BB 8
#define TT 16
#define CIN 32
#define HID 64
#define HH 64
#define WW 64
#define EPS 1e-3f
#define NEG_SLOPE 0.01f

typedef short s16x8 __attribute__((ext_vector_type(8)));
typedef __bf16 bfx8 __attribute__((ext_vector_type(8)));
typedef float fx4 __attribute__((ext_vector_type(4)));

__device__ __forceinline__ unsigned short f2bf(float f) {
    union { float f; unsigned u; } v; v.f = f;
    unsigned r = v.u + 0x7fffu + ((v.u >> 16) & 1u);
    return (unsigned short)(r >> 16);
}
__device__ __forceinline__ float bf2f(unsigned short b) {
    union { unsigned u; float f; } v; v.u = ((unsigned)b) << 16;
    return v.f;
}
__device__ __forceinline__ float tanh_fast(float x) {
    x = fminf(fmaxf(x, -15.f), 15.f);
    float e = __expf(-2.f * x);
    return (1.f - e) / (1.f + e);
}

// x (NCHW fp32) -> xcl [b][t][y*64+x][32] bf16
__global__ __launch_bounds__(256) void x2bf(const float* __restrict__ x,
                                            unsigned short* __restrict__ xcl) {
    __shared__ float s[32][65];
    int y = blockIdx.x, t = blockIdx.y, b = blockIdx.z;
    int tid = threadIdx.x;
    const float* src = x + (((size_t)(b * TT + t) * CIN) * HH + y) * WW;
#pragma unroll
    for (int k = 0; k < 8; ++k) {
        int idx = tid + k * 256;
        int c = idx >> 6, xx = idx & 63;
        s[c][xx] = src[(size_t)c * HH * WW + xx];
    }
    __syncthreads();
    int xx = tid >> 2, c0 = (tid & 3) * 8;
    unsigned short tmp[8];
#pragma unroll
    for (int j = 0; j < 8; ++j) tmp[j] = f2bf(s[c0 + j][xx]);
    unsigned short* dst = xcl + (((size_t)(b * TT + t) * 4096) + y * 64 + xx) * 32 + c0;
    *(s16x8*)dst = *(s16x8*)tmp;
}

// w [256 oc][96 ch][3][3] fp32 -> wpkb [n(256)][tap(9)][ch(96)] bf16
// n-mapping: gate=(n>>4)&3, hid=(n>>6)*16+(n&15), oc=gate*64+hid
__global__ __launch_bounds__(256) void pack_wb(const float* __restrict__ w,
                                               unsigned short* __restrict__ wpkb) {
    int idx = blockIdx.x * 256 + threadIdx.x;
    if (idx >= 256 * 864) return;
    int ks = idx % 96; int u = idx / 96;
    int tap = u % 9;   int n = u / 9;
    int gate = (n >> 4) & 3;
    int hid  = (n >> 6) * 16 + (n & 15);
    int oc   = gate * 64 + hid;
    wpkb[idx] = f2bf(w[((size_t)oc * 96 + ks) * 9 + tap]);
}

// 9-tap GEMM over one staged K-chunk. sec = B k-offset within tap's 96.
template <int CHP, bool HAS_LO>
__device__ __forceinline__ void do_taps(const unsigned short* s_a,
                                        const unsigned short* __restrict__ wpkb,
                                        fx4 (&acc)[8][4],
                                        int lane15, int kq, int w4, int sec) {
#pragma unroll
    for (int tap = 0; tap < 9; ++tap) {
        const int ky = tap / 3, kx = tap % 3;
        bfx8 bf[4];
#pragma unroll
        for (int g = 0; g < 4; ++g) {
            int n = (4 * w4 + g) * 16 + lane15;
            bf[g] = *(const bfx8*)(wpkb + (size_t)n * 864 + tap * 96 + sec + kq * 8);
        }
        bfx8 af[8];
#pragma unroll
        for (int m = 0; m < 8; ++m) {
            int row = (m >> 2) + ky;
            int col = (m & 3) * 16 + lane15 + kx;
            af[m] = *(const bfx8*)(s_a + (row * 66 + col) * CHP + kq * 8);
        }
#pragma unroll
        for (int m = 0; m < 8; ++m)
#pragma unroll
            for (int g = 0; g < 4; ++g)
                acc[m][g] = __builtin_amdgcn_mfma_f32_16x16x32_bf16(af[m], bf[g], acc[m][g], 0, 0, 0);
        if (HAS_LO) {
#pragma unroll
            for (int m = 0; m < 8; ++m) {
                int row = (m >> 2) + ky;
                int col = (m & 3) * 16 + lane15 + kx;
                af[m] = *(const bfx8*)(s_a + (row * 66 + col) * CHP + 32 + kq * 8);
            }
#pragma unroll
            for (int m = 0; m < 8; ++m)
#pragma unroll
                for (int g = 0; g < 4; ++g)
                    acc[m][g] = __builtin_amdgcn_mfma_f32_16x16x32_bf16(af[m], bf[g], acc[m][g], 0, 0, 0);
        }
    }
}

// One timestep. grid (32 ypairs, 8 b), 256 thr (4 waves), 1 block/CU.
// M=128 pixels (rows y0,y0+1), N=256 (4 gates x 64 hid). K=160/tap x 9 taps.
// hcl pixel layout (128 ch): [h_hi j<32][h_lo j<32][h_hi j>=32][h_lo j>=32]
__global__ __launch_bounds__(256, 1) void lstm_step(
    const unsigned short* __restrict__ xcl,
    const unsigned short* __restrict__ wpkb,
    const float* __restrict__ bias,
    const unsigned short* __restrict__ h_in,
    unsigned short* __restrict__ h_out,
    float* __restrict__ c_ws,
    float* __restrict__ out,
    float* __restrict__ partial,
    int t) {
    const int yp = blockIdx.x, b = blockIdx.y;
    const int y0 = yp * 2;
    const int tid = threadIdx.x;
    const int lane15 = tid & 15;
    const int kq = (tid >> 4) & 3;
    const int w4 = tid >> 6;

    __shared__ __align__(16) unsigned short s_a[4 * 66 * 72];   // 38016 B

    fx4 acc[8][4];
#pragma unroll
    for (int m = 0; m < 8; ++m)
#pragma unroll
        for (int g = 0; g < 4; ++g) acc[m][g] = (fx4)0.f;

    // ---- Phase X: stage x-tile (4 rows x 66 x 32ch @ stride 40) ----
    for (int u = tid; u < 4 * 66 * 4; u += 256) {
        int unit = u & 3, pix = u >> 2;
        int col = pix % 66, r = pix / 66;
        int iy = y0 + r - 1, ix = col - 1;
        s16x8 v = (s16x8)0;
        if (iy >= 0 && iy < 64 && ix >= 0 && ix < 64)
            v = *(const s16x8*)(xcl + (((size_t)(b * TT + t) * 4096) + iy * 64 + ix) * 32 + unit * 8);
        *(s16x8*)(s_a + (r * 66 + col) * 40 + unit * 8) = v;
    }
    __syncthreads();
    do_taps<40, false>(s_a, wpkb, acc, lane15, kq, w4, 0);
    __syncthreads();

    // ---- Phase HA: stage hcl ch [0..64) (h j<32 hi+lo) @ stride 72 ----
    for (int u = tid; u < 4 * 66 * 8; u += 256) {
        int unit = u & 7, pix = u >> 3;
        int col = pix % 66, r = pix / 66;
        int iy = y0 + r - 1, ix = col - 1;
        s16x8 v = (s16x8)0;
        if (iy >= 0 && iy < 64 && ix >= 0 && ix < 64)
            v = *(const s16x8*)(h_in + ((size_t)(b * 64 + iy) * 64 + ix) * 128 + unit * 8);
        *(s16x8*)(s_a + (r * 66 + col) * 72 + unit * 8) = v;
    }
    __syncthreads();
    do_taps<72, true>(s_a, wpkb, acc, lane15, kq, w4, 32);
    __syncthreads();

    // ---- Phase HB: stage hcl ch [64..128) (h j>=32 hi+lo) ----
    for (int u = tid; u < 4 * 66 * 8; u += 256) {
        int unit = u & 7, pix = u >> 3;
        int col = pix % 66, r = pix / 66;
        int iy = y0 + r - 1, ix = col - 1;
        s16x8 v = (s16x8)0;
        if (iy >= 0 && iy < 64 && ix >= 0 && ix < 64)
            v = *(const s16x8*)(h_in + ((size_t)(b * 64 + iy) * 64 + ix) * 128 + 64 + unit * 8);
        *(s16x8*)(s_a + (r * 66 + col) * 72 + unit * 8) = v;
    }
    __syncthreads();
    do_taps<72, true>(s_a, wpkb, acc, lane15, kq, w4, 64);

    // ---- Epilogue: LSTM gate math; lane owns hid = 16*w4 + lane15 ----
    const int hid = w4 * 16 + lane15;
    const float bi = bias[0 * 64 + hid], bff = bias[1 * 64 + hid];
    const float bo = bias[2 * 64 + hid], bg = bias[3 * 64 + hid];
    const int chh = (hid < 32) ? hid : hid + 32;
    float osum = 0.f, osum2 = 0.f;
#pragma unroll
    for (int m = 0; m < 8; ++m) {
        int yy = y0 + (m >> 2);
        int xb = (m & 3) * 16 + kq * 4;
        size_t pixbase = (size_t)(b * 64 + yy) * 64 + xb;
        float4 o4;
#pragma unroll
        for (int r = 0; r < 4; ++r) {
            float ci = acc[m][0][r] + bi;
            float cf = acc[m][1][r] + bff;
            float co = acc[m][2][r] + bo;
            float cg = acc[m][3][r] + bg;
            size_t ca = (pixbase + r) * 64 + hid;
            float c_old = c_ws[ca];
            float si = 1.f / (1.f + __expf(-ci));
            float sf = 1.f / (1.f + __expf(-cf));
            float so = 1.f / (1.f + __expf(-co));
            float c_new = sf * c_old + si * tanh_fast(cg);
            float h = so * tanh_fast(c_new);
            c_ws[ca] = c_new;
            unsigned short hh = f2bf(h);
            unsigned short hl = f2bf(h - bf2f(hh));
            unsigned short* hp = h_out + (pixbase + r) * 128;
            hp[chh] = hh;
            hp[chh + 32] = hl;
            float ov = (h >= 0.f) ? h : NEG_SLOPE * h;
            (&o4.x)[r] = ov;
            osum += ov;
            osum2 += ov * ov;
        }
        *(float4*)(out + (((size_t)(b * TT + t) * 64 + hid) * 64 + yy) * 64 + xb) = o4;
    }
    osum  += __shfl_xor(osum, 16);  osum  += __shfl_xor(osum, 32);
    osum2 += __shfl_xor(osum2, 16); osum2 += __shfl_xor(osum2, 32);
    if (kq == 0) {
        int bid = b * 32 + yp;
        partial[bid * 128 + hid] += osum;
        partial[bid * 128 + 64 + hid] += osum2;
    }
}

__global__ void finalize_stats(const float* __restrict__ partial,
                               float* __restrict__ stats,
                               const float* __restrict__ gamma,
                               const float* __restrict__ beta) {
    int idx = threadIdx.x & 127;
    int seg = threadIdx.x >> 7;
    float s = 0.f;
    for (int k = seg * 128; k < seg * 128 + 128; ++k) s += partial[k * 128 + idx];
    __shared__ float red[2][128];
    red[seg][idx] = s;
    __syncthreads();
    if (threadIdx.x < 64) {
        int hid = threadIdx.x;
        const float n = (float)((size_t)BB * TT * HH * WW);
        float mean = (red[0][hid] + red[1][hid]) / n;
        float var  = (red[0][64 + hid] + red[1][64 + hid]) / n - mean * mean;
        float inv  = rsqrtf(var + EPS);
        float sc   = gamma[hid] * inv;
        stats[hid]      = sc;
        stats[64 + hid] = beta[hid] - mean * sc;
    }
}

__global__ __launch_bounds__(256) void normalize_k(float* __restrict__ out,
                                                   const float* __restrict__ stats) {
    const size_t N = (size_t)BB * TT * HID * HH * WW;
    size_t i = ((size_t)blockIdx.x * blockDim.x + threadIdx.x) * 4;
    size_t stride = (size_t)gridDim.x * blockDim.x * 4;
    for (; i < N; i += stride) {
        int ch = (int)((i >> 12) & (HID - 1));
        float sc = stats[ch], sh = stats[64 + ch];
        float4 v = *(float4*)(out + i);
        v.x = fmaf(v.x, sc, sh);
        v.y = fmaf(v.y, sc, sh);
        v.z = fmaf(v.z, sc, sh);
        v.w = fmaf(v.w, sc, sh);
        *(float4*)(out + i) = v;
    }
}

extern "C" void kernel_launch(void* const* d_in, const int* in_sizes, int n_in,
                              void* d_out, int out_size, void* d_ws, size_t ws_size,
                              hipStream_t stream) {
    const float* x     = (const float*)d_in[0];
    const float* w     = (const float*)d_in[1];
    const float* bias  = (const float*)d_in[2];
    const float* gamma = (const float*)d_in[3];
    const float* beta  = (const float*)d_in[4];
    float* out = (float*)d_out;
    char* wsb = (char*)d_ws;

    unsigned short* xcl  = (unsigned short*)(wsb);                    // 33,554,432 B
    unsigned short* wpkb = (unsigned short*)(wsb + 33554432);         //    442,368 B
    unsigned short* hA   = (unsigned short*)(wsb + 33996800);         //  8,388,608 B
    unsigned short* hB   = (unsigned short*)(wsb + 42385408);         //  8,388,608 B
    float* c_ws          = (float*)(wsb + 50774016);                  //  8,388,608 B
    float* partial       = (float*)(wsb + 59162624);                  // 256*128*4 + 512 B
    float* stats         = partial + 256 * 128;

    hipMemsetAsync(hA, 0, 8388608, stream);
    hipMemsetAsync(c_ws, 0, 8388608, stream);
    hipMemsetAsync(partial, 0, (256 * 128 + 128) * 4, stream);

    x2bf<<<dim3(64, 16, 8), 256, 0, stream>>>(x, xcl);
    pack_wb<<<864, 256, 0, stream>>>(w, wpkb);

    unsigned short* hin = hA;
    unsigned short* hout = hB;
    for (int t = 0; t < TT; ++t) {
        lstm_step<<<dim3(32, 8), 256, 0, stream>>>(xcl, wpkb, bias, hin, hout,
                                                   c_ws, out, partial, t);
        unsigned short* tmp = hin; hin = hout; hout = tmp;
    }
    finalize_stats<<<1, 256, 0, stream>>>(partial, stats, gamma, beta);
    normalize_k<<<8192, 256, 0, stream>>>(out, stats);
}